// Round 1
// baseline (1115.373 us; speedup 1.0000x reference)
//
#include <hip/hip_runtime.h>
#include <hip/hip_bf16.h>
#include <math.h>

#define B_   16
#define C_   384
#define C3_  1152
#define HW_  4096
#define NH_  8
#define D_   48

// ---------------- SGEMM: C[b](M x 4096) = W(M x K) * X[b](K x 4096) ----------------
// 128x128 tile, BK=8, 256 threads, 8x8 per thread, fp32.
template<int M, int K>
__global__ __launch_bounds__(256) void sgemm_wx(
    const float* __restrict__ W, const float* __restrict__ X,
    float* __restrict__ C, long long xstride, long long cstride)
{
    __shared__ float As[8][128];
    __shared__ float Bs[8][128];
    const int b  = blockIdx.z;
    const int m0 = blockIdx.y * 128;
    const int n0 = blockIdx.x * 128;
    const float* Xb = X + (size_t)b * xstride;
    float* Cb = C + (size_t)b * cstride;
    const int t = threadIdx.x;
    const int arow = t >> 1, acol = (t & 1) * 4;
    const int brow = t >> 5, bcol = (t & 31) * 4;
    const int tx = t & 15, ty = t >> 4;

    float acc[8][8];
    #pragma unroll
    for (int i = 0; i < 8; ++i)
        #pragma unroll
        for (int j = 0; j < 8; ++j) acc[i][j] = 0.f;

    for (int k0 = 0; k0 < K; k0 += 8) {
        float4 av = *(const float4*)&W[(size_t)(m0 + arow) * K + k0 + acol];
        float4 bv = *(const float4*)&Xb[(size_t)(k0 + brow) * HW_ + n0 + bcol];
        As[acol + 0][arow] = av.x;
        As[acol + 1][arow] = av.y;
        As[acol + 2][arow] = av.z;
        As[acol + 3][arow] = av.w;
        *(float4*)&Bs[brow][bcol] = bv;
        __syncthreads();
        #pragma unroll
        for (int kk = 0; kk < 8; ++kk) {
            float a[8], bb[8];
            *(float4*)(a)      = *(const float4*)&As[kk][ty * 8];
            *(float4*)(a + 4)  = *(const float4*)&As[kk][ty * 8 + 4];
            *(float4*)(bb)     = *(const float4*)&Bs[kk][tx * 8];
            *(float4*)(bb + 4) = *(const float4*)&Bs[kk][tx * 8 + 4];
            #pragma unroll
            for (int i = 0; i < 8; ++i)
                #pragma unroll
                for (int j = 0; j < 8; ++j)
                    acc[i][j] = fmaf(a[i], bb[j], acc[i][j]);
        }
        __syncthreads();
    }
    #pragma unroll
    for (int i = 0; i < 8; ++i) {
        int row = m0 + ty * 8 + i;
        float4 v0 = make_float4(acc[i][0], acc[i][1], acc[i][2], acc[i][3]);
        float4 v1 = make_float4(acc[i][4], acc[i][5], acc[i][6], acc[i][7]);
        *(float4*)&Cb[(size_t)row * HW_ + n0 + tx * 8]     = v0;
        *(float4*)&Cb[(size_t)row * HW_ + n0 + tx * 8 + 4] = v1;
    }
}

// ---------------- depthwise 3x3, SAME, in-place via full-plane LDS ----------------
__global__ __launch_bounds__(256) void dwconv_inplace(
    float* __restrict__ buf, const float* __restrict__ wdw)
{
    const int plane = blockIdx.x;           // b*1152 + ch
    const int ch = plane % C3_;
    __shared__ float sm[64 * 64];
    float* g = buf + (size_t)plane * HW_;
    const int t = threadIdx.x;
    #pragma unroll
    for (int i = 0; i < 4; ++i)
        *(float4*)&sm[t * 4 + i * 1024] = *(const float4*)&g[t * 4 + i * 1024];
    float w[9];
    #pragma unroll
    for (int j = 0; j < 9; ++j) w[j] = wdw[ch * 9 + j];
    __syncthreads();
    #pragma unroll
    for (int i = 0; i < 16; ++i) {
        const int idx = i * 256 + t;
        const int y = idx >> 6, x = idx & 63;
        float s = 0.f;
        #pragma unroll
        for (int ky = 0; ky < 3; ++ky) {
            const int yy = y + ky - 1;
            if (yy < 0 || yy > 63) continue;
            #pragma unroll
            for (int kx = 0; kx < 3; ++kx) {
                const int xx = x + kx - 1;
                if (xx < 0 || xx > 63) continue;
                s = fmaf(w[ky * 3 + kx], sm[yy * 64 + xx], s);
            }
        }
        g[idx] = s;   // write to GLOBAL; reads come from LDS -> no hazard
    }
}

// ---------------- per-row 1/max(||.||,eps) for q and k ----------------
__global__ __launch_bounds__(256) void rownorm(
    const float* __restrict__ buf, float* __restrict__ nqinv, float* __restrict__ nkinv)
{
    const int r = blockIdx.x;               // 0..12287 ; first 6144 = q rows
    const int isk = (r >= 6144) ? 1 : 0;
    const int rr = isk ? (r - 6144) : r;    // b*384 + (h*48+d)
    const int b = rr / C_, chIn = rr % C_;
    const float* g = buf + ((size_t)b * C3_ + (size_t)isk * C_ + chIn) * HW_;
    const int t = threadIdx.x;
    float s = 0.f;
    #pragma unroll
    for (int i = 0; i < 4; ++i) {
        float4 v = *(const float4*)&g[t * 4 + i * 1024];
        s += v.x * v.x + v.y * v.y + v.z * v.z + v.w * v.w;
    }
    #pragma unroll
    for (int m = 1; m < 64; m <<= 1) s += __shfl_xor(s, m);
    __shared__ float wsum[4];
    if ((t & 63) == 0) wsum[t >> 6] = s;
    __syncthreads();
    if (t == 0) {
        float tot = wsum[0] + wsum[1] + wsum[2] + wsum[3];
        float inv = 1.f / fmaxf(sqrtf(tot), 1e-12f);
        (isk ? nkinv : nqinv)[rr] = inv;
    }
}

// ---------------- raw scores partials: sp[ks][bh][48][48] ----------------
__global__ __launch_bounds__(256) void scores_partial(
    const float* __restrict__ buf, float* __restrict__ sp)
{
    const int bh = blockIdx.x;              // 0..127
    const int ks = blockIdx.y;              // 0..7
    const int b = bh >> 3, h = bh & 7;
    const float* qbase = buf + ((size_t)b * C3_ + (size_t)h * D_) * HW_;
    const float* kbase = qbase + (size_t)C_ * HW_;
    __shared__ float qs[48][65];
    __shared__ float ksm[48][65];
    const int t = threadIdx.x;
    const int d0 = (t >> 4) * 3, e0 = (t & 15) * 3;
    float acc[3][3] = {{0.f}};
    for (int kc = ks * 512; kc < ks * 512 + 512; kc += 64) {
        #pragma unroll
        for (int i = 0; i < 3; ++i) {
            const int idx = i * 256 + t;    // 0..767
            const int row = idx >> 4, col = (idx & 15) * 4;
            float4 qv = *(const float4*)&qbase[(size_t)row * HW_ + kc + col];
            qs[row][col] = qv.x; qs[row][col+1] = qv.y; qs[row][col+2] = qv.z; qs[row][col+3] = qv.w;
            float4 kv = *(const float4*)&kbase[(size_t)row * HW_ + kc + col];
            ksm[row][col] = kv.x; ksm[row][col+1] = kv.y; ksm[row][col+2] = kv.z; ksm[row][col+3] = kv.w;
        }
        __syncthreads();
        #pragma unroll 8
        for (int kk = 0; kk < 64; ++kk) {
            float q0 = qs[d0][kk], q1 = qs[d0+1][kk], q2 = qs[d0+2][kk];
            float k0 = ksm[e0][kk], k1 = ksm[e0+1][kk], k2 = ksm[e0+2][kk];
            acc[0][0] = fmaf(q0, k0, acc[0][0]); acc[0][1] = fmaf(q0, k1, acc[0][1]); acc[0][2] = fmaf(q0, k2, acc[0][2]);
            acc[1][0] = fmaf(q1, k0, acc[1][0]); acc[1][1] = fmaf(q1, k1, acc[1][1]); acc[1][2] = fmaf(q1, k2, acc[1][2]);
            acc[2][0] = fmaf(q2, k0, acc[2][0]); acc[2][1] = fmaf(q2, k1, acc[2][1]); acc[2][2] = fmaf(q2, k2, acc[2][2]);
        }
        __syncthreads();
    }
    float* out = sp + ((size_t)ks * 128 + bh) * (D_ * D_);
    #pragma unroll
    for (int i = 0; i < 3; ++i)
        #pragma unroll
        for (int j = 0; j < 3; ++j)
            out[(d0 + i) * D_ + e0 + j] = acc[i][j];
}

// ---------------- reduce partials, scale by inv-norms & temperature, softmax ----------------
__global__ __launch_bounds__(64) void softmax_k(
    const float* __restrict__ sp, const float* __restrict__ nqinv,
    const float* __restrict__ nkinv, const float* __restrict__ temp,
    float* __restrict__ attn)
{
    const int row = blockIdx.x;             // (b*8+h)*48 + d
    const int bh = row / D_, d = row % D_;
    const int h = bh & 7;
    const int e = threadIdx.x;
    float s = -INFINITY;
    if (e < D_) {
        float raw = 0.f;
        #pragma unroll
        for (int ks = 0; ks < 8; ++ks)
            raw += sp[((size_t)ks * 128 + bh) * (D_ * D_) + d * D_ + e];
        s = raw * nqinv[bh * D_ + d] * nkinv[bh * D_ + e] * temp[h];
    }
    float m = s;
    #pragma unroll
    for (int off = 1; off < 64; off <<= 1) m = fmaxf(m, __shfl_xor(m, off));
    float p = (e < D_) ? expf(s - m) : 0.f;
    float sum = p;
    #pragma unroll
    for (int off = 1; off < 64; off <<= 1) sum += __shfl_xor(sum, off);
    if (e < D_) attn[(size_t)bh * (D_ * D_) + d * D_ + e] = p / sum;
}

// ---------------- out[b,h*48+d,p] = sum_e attn[d,e] * v[e,p]; 2 cols/thread ----------------
__global__ __launch_bounds__(256) void pv_kernel(
    const float* __restrict__ buf, const float* __restrict__ attn,
    float* __restrict__ outbuf)
{
    const int b = blockIdx.z, h = blockIdx.y;
    const int p0 = blockIdx.x * 512 + threadIdx.x * 2;
    __shared__ float a4[48][48];
    const float* ab = attn + ((size_t)b * 8 + h) * (D_ * D_);
    for (int i = threadIdx.x; i < D_ * D_; i += 256) ((float*)a4)[i] = ab[i];
    __syncthreads();
    const float* vbase = buf + ((size_t)b * C3_ + 2 * C_ + (size_t)h * D_) * HW_;
    float2 acc[48];
    #pragma unroll
    for (int d = 0; d < 48; ++d) { acc[d].x = 0.f; acc[d].y = 0.f; }
    #pragma unroll 1
    for (int e4 = 0; e4 < 12; ++e4) {
        float2 vv[4];
        #pragma unroll
        for (int j = 0; j < 4; ++j)
            vv[j] = *(const float2*)&vbase[(size_t)(e4 * 4 + j) * HW_ + p0];
        #pragma unroll
        for (int d = 0; d < 48; ++d) {
            float4 a = *(const float4*)&a4[d][e4 * 4];
            acc[d].x = fmaf(a.x, vv[0].x, fmaf(a.y, vv[1].x, fmaf(a.z, vv[2].x, fmaf(a.w, vv[3].x, acc[d].x))));
            acc[d].y = fmaf(a.x, vv[0].y, fmaf(a.y, vv[1].y, fmaf(a.z, vv[2].y, fmaf(a.w, vv[3].y, acc[d].y))));
        }
    }
    float* obase = outbuf + ((size_t)b * C3_ + (size_t)h * D_) * HW_;
    #pragma unroll
    for (int d = 0; d < 48; ++d)
        *(float2*)&obase[(size_t)d * HW_ + p0] = acc[d];
}

extern "C" void kernel_launch(void* const* d_in, const int* in_sizes, int n_in,
                              void* d_out, int out_size, void* d_ws, size_t ws_size,
                              hipStream_t stream)
{
    const float* x      = (const float*)d_in[0];   // (16,384,64,64)
    const float* w_qkv  = (const float*)d_in[1];   // (1152,384)
    const float* w_dw   = (const float*)d_in[2];   // (1152,1,3,3)
    const float* w_proj = (const float*)d_in[3];   // (384,384)
    const float* temp   = (const float*)d_in[4];   // (1,8,1,1)
    float* out = (float*)d_out;                    // (16,384,64,64)

    float* buf   = (float*)d_ws;                          // 16*1152*4096 = 75,497,472 f
    float* nqinv = buf + (size_t)B_ * C3_ * HW_;          // 6144 f
    float* nkinv = nqinv + 6144;                          // 6144 f
    float* sp    = nkinv + 6144;                          // 8*128*2304 = 2,359,296 f
    float* attn  = sp + (size_t)8 * 128 * D_ * D_;        // 128*2304 = 294,912 f

    // 1) qkv = w_qkv @ x  (per-batch GEMM 1152x384x4096)
    sgemm_wx<C3_, C_><<<dim3(32, 9, 16), 256, 0, stream>>>(
        w_qkv, x, buf, (long long)C_ * HW_, (long long)C3_ * HW_);

    // 2) depthwise 3x3 SAME, in place
    dwconv_inplace<<<B_ * C3_, 256, 0, stream>>>(buf, w_dw);

    // 3) q,k row inverse-norms
    rownorm<<<2 * 6144, 256, 0, stream>>>(buf, nqinv, nkinv);

    // 4) raw scores partials (K split 8)
    scores_partial<<<dim3(128, 8), 256, 0, stream>>>(buf, sp);

    // 5) reduce + scale + softmax
    softmax_k<<<6144, 64, 0, stream>>>(sp, nqinv, nkinv, temp, attn);

    // 6) attn @ v -> writes into q region of buf (free by now)
    pv_kernel<<<dim3(8, 8, 16), 256, 0, stream>>>(buf, attn, buf);

    // 7) out = w_proj @ attn_out (per-batch GEMM 384x384x4096)
    sgemm_wx<C_, C_><<<dim3(32, 3, 16), 256, 0, stream>>>(
        w_proj, buf, out, (long long)C3_ * HW_, (long long)C_ * HW_);
}

// Round 2
// 462.363 us; speedup vs baseline: 2.4123x; 2.4123x over previous
//
#include <hip/hip_runtime.h>
#include <hip/hip_bf16.h>
#include <math.h>

#define B_   16
#define C_   384
#define C3_  1152
#define HW_  4096
#define NH_  8
#define D_   48

typedef __bf16 bf16x8 __attribute__((ext_vector_type(8)));
typedef float  f32x4  __attribute__((ext_vector_type(4)));

__device__ __forceinline__ unsigned short f2bf(float f) {
    union { float f; unsigned u; } v; v.f = f;
    unsigned r = v.u + 0x7fff + ((v.u >> 16) & 1);   // RTNE
    return (unsigned short)(r >> 16);
}

// ---------------- fp32 -> bf16 weight conversion ----------------
__global__ __launch_bounds__(256) void conv_w_bf16(
    const float* __restrict__ w, unsigned short* __restrict__ wb, int n4)
{
    int i = blockIdx.x * 256 + threadIdx.x;
    if (i < n4) {
        float4 v = *(const float4*)&w[(size_t)i * 4];
        unsigned short t[4] = { f2bf(v.x), f2bf(v.y), f2bf(v.z), f2bf(v.w) };
        *(uint2*)&wb[(size_t)i * 4] = *(uint2*)t;
    }
}

// ---------------- x [b][384][4096] f32 -> xt [b][4096][384] bf16 ----------------
__global__ __launch_bounds__(256) void transpose_to_bf16(
    const float* __restrict__ x, unsigned short* __restrict__ xt)
{
    const int b  = blockIdx.z;
    const int k0 = blockIdx.y * 64;
    const int n0 = blockIdx.x * 64;
    __shared__ float sm[64][65];
    const float* xb = x + (size_t)b * C_ * HW_;
    unsigned short* xtb = xt + (size_t)b * HW_ * C_;
    const int t = threadIdx.x;
    #pragma unroll
    for (int i = 0; i < 4; ++i) {
        int row = (t >> 4) + i * 16;
        int col = (t & 15) * 4;
        float4 v = *(const float4*)&xb[(size_t)(k0 + row) * HW_ + n0 + col];
        sm[row][col] = v.x; sm[row][col+1] = v.y; sm[row][col+2] = v.z; sm[row][col+3] = v.w;
    }
    __syncthreads();
    #pragma unroll
    for (int i = 0; i < 2; ++i) {
        int nl = (t >> 3) + i * 32;
        int ks = (t & 7) * 8;
        unsigned short tmp[8];
        #pragma unroll
        for (int j = 0; j < 8; ++j) tmp[j] = f2bf(sm[ks + j][nl]);
        *(uint4*)&xtb[(size_t)(n0 + nl) * C_ + k0 + ks] = *(uint4*)tmp;
    }
}

// ---------------- bf16 MFMA GEMM: C[b](M x 4096) = W(M x 384) * XT[b](4096 x 384)^T ----------------
// 128x128 tile, BK=32, 4 waves, each wave 64x64 via 4x4 frags of 16x16x32.
template<int M>
__global__ __launch_bounds__(256) void mfma_gemm(
    const unsigned short* __restrict__ Wb,
    const unsigned short* __restrict__ XT,
    float* __restrict__ C, long long xstride, long long cstride)
{
    constexpr int K = 384;
    __shared__ unsigned short As[128 * 32];
    __shared__ unsigned short Bs[128 * 32];
    const int b  = blockIdx.z;
    const int m0 = blockIdx.y * 128;
    const int n0 = blockIdx.x * 128;
    const unsigned short* XTb = XT + (size_t)b * xstride;
    float* Cb = C + (size_t)b * cstride;
    const int t = threadIdx.x;
    const int l = t & 63, w = t >> 6;
    const int wr = w >> 1, wc = w & 1;
    const int frow = l & 15, kseg = (l >> 4) * 8;
    const int srow = t >> 2, sseg = (t & 3) * 8;

    f32x4 acc[4][4] = {};

    for (int k0 = 0; k0 < K; k0 += 32) {
        __syncthreads();   // previous iter's LDS reads done before overwrite
        #pragma unroll
        for (int i = 0; i < 2; ++i) {
            const unsigned short* ga = Wb + (size_t)(m0 + srow + i * 64) * K + k0 + sseg;
            const unsigned short* gb = XTb + (size_t)(n0 + srow + i * 64) * K + k0 + sseg;
            __builtin_amdgcn_global_load_lds(
                (const __attribute__((address_space(1))) void*)ga,
                (__attribute__((address_space(3))) void*)((char*)As + w * 1024 + i * 4096),
                16, 0, 0);
            __builtin_amdgcn_global_load_lds(
                (const __attribute__((address_space(1))) void*)gb,
                (__attribute__((address_space(3))) void*)((char*)Bs + w * 1024 + i * 4096),
                16, 0, 0);
        }
        __syncthreads();   // compiler drains vmcnt before barrier
        bf16x8 af[4], bfr[4];
        #pragma unroll
        for (int mi = 0; mi < 4; ++mi)
            af[mi] = *(const bf16x8*)&As[(wr * 64 + mi * 16 + frow) * 32 + kseg];
        #pragma unroll
        for (int ni = 0; ni < 4; ++ni)
            bfr[ni] = *(const bf16x8*)&Bs[(wc * 64 + ni * 16 + frow) * 32 + kseg];
        #pragma unroll
        for (int mi = 0; mi < 4; ++mi)
            #pragma unroll
            for (int ni = 0; ni < 4; ++ni)
                acc[mi][ni] = __builtin_amdgcn_mfma_f32_16x16x32_bf16(
                    af[mi], bfr[ni], acc[mi][ni], 0, 0, 0);
    }
    const int crow = (l >> 4) * 4;
    const int ccol = l & 15;
    #pragma unroll
    for (int mi = 0; mi < 4; ++mi)
        #pragma unroll
        for (int ni = 0; ni < 4; ++ni) {
            float* cp = &Cb[(size_t)(m0 + wr * 64 + mi * 16 + crow) * HW_ + n0 + wc * 64 + ni * 16 + ccol];
            #pragma unroll
            for (int r = 0; r < 4; ++r)
                cp[(size_t)r * HW_] = acc[mi][ni][r];
        }
}

// ---------------- depthwise 3x3, SAME, in-place via full-plane LDS ----------------
__global__ __launch_bounds__(256) void dwconv_inplace(
    float* __restrict__ buf, const float* __restrict__ wdw)
{
    const int plane = blockIdx.x;
    const int ch = plane % C3_;
    __shared__ float sm[64 * 64];
    float* g = buf + (size_t)plane * HW_;
    const int t = threadIdx.x;
    #pragma unroll
    for (int i = 0; i < 4; ++i)
        *(float4*)&sm[t * 4 + i * 1024] = *(const float4*)&g[t * 4 + i * 1024];
    float w[9];
    #pragma unroll
    for (int j = 0; j < 9; ++j) w[j] = wdw[ch * 9 + j];
    __syncthreads();
    #pragma unroll
    for (int i = 0; i < 16; ++i) {
        const int idx = i * 256 + t;
        const int y = idx >> 6, x = idx & 63;
        float s = 0.f;
        #pragma unroll
        for (int ky = 0; ky < 3; ++ky) {
            const int yy = y + ky - 1;
            if (yy < 0 || yy > 63) continue;
            #pragma unroll
            for (int kx = 0; kx < 3; ++kx) {
                const int xx = x + kx - 1;
                if (xx < 0 || xx > 63) continue;
                s = fmaf(w[ky * 3 + kx], sm[yy * 64 + xx], s);
            }
        }
        g[idx] = s;
    }
}

// ---------------- per-row 1/max(||.||,eps) for q and k ----------------
__global__ __launch_bounds__(256) void rownorm(
    const float* __restrict__ buf, float* __restrict__ nqinv, float* __restrict__ nkinv)
{
    const int r = blockIdx.x;
    const int isk = (r >= 6144) ? 1 : 0;
    const int rr = isk ? (r - 6144) : r;
    const int b = rr / C_, chIn = rr % C_;
    const float* g = buf + ((size_t)b * C3_ + (size_t)isk * C_ + chIn) * HW_;
    const int t = threadIdx.x;
    float s = 0.f;
    #pragma unroll
    for (int i = 0; i < 4; ++i) {
        float4 v = *(const float4*)&g[t * 4 + i * 1024];
        s += v.x * v.x + v.y * v.y + v.z * v.z + v.w * v.w;
    }
    #pragma unroll
    for (int m = 1; m < 64; m <<= 1) s += __shfl_xor(s, m);
    __shared__ float wsum[4];
    if ((t & 63) == 0) wsum[t >> 6] = s;
    __syncthreads();
    if (t == 0) {
        float tot = wsum[0] + wsum[1] + wsum[2] + wsum[3];
        float inv = 1.f / fmaxf(sqrtf(tot), 1e-12f);
        (isk ? nkinv : nqinv)[rr] = inv;
    }
}

// ---------------- raw scores partials: sp[ks][bh][48][48] ----------------
__global__ __launch_bounds__(256) void scores_partial(
    const float* __restrict__ buf, float* __restrict__ sp)
{
    const int bh = blockIdx.x;
    const int ks = blockIdx.y;
    const int b = bh >> 3, h = bh & 7;
    const float* qbase = buf + ((size_t)b * C3_ + (size_t)h * D_) * HW_;
    const float* kbase = qbase + (size_t)C_ * HW_;
    __shared__ float qs[48][65];
    __shared__ float ksm[48][65];
    const int t = threadIdx.x;
    const int d0 = (t >> 4) * 3, e0 = (t & 15) * 3;
    float acc[3][3] = {{0.f}};
    for (int kc = ks * 512; kc < ks * 512 + 512; kc += 64) {
        #pragma unroll
        for (int i = 0; i < 3; ++i) {
            const int idx = i * 256 + t;
            const int row = idx >> 4, col = (idx & 15) * 4;
            float4 qv = *(const float4*)&qbase[(size_t)row * HW_ + kc + col];
            qs[row][col] = qv.x; qs[row][col+1] = qv.y; qs[row][col+2] = qv.z; qs[row][col+3] = qv.w;
            float4 kv = *(const float4*)&kbase[(size_t)row * HW_ + kc + col];
            ksm[row][col] = kv.x; ksm[row][col+1] = kv.y; ksm[row][col+2] = kv.z; ksm[row][col+3] = kv.w;
        }
        __syncthreads();
        #pragma unroll 8
        for (int kk = 0; kk < 64; ++kk) {
            float q0 = qs[d0][kk], q1 = qs[d0+1][kk], q2 = qs[d0+2][kk];
            float k0 = ksm[e0][kk], k1 = ksm[e0+1][kk], k2 = ksm[e0+2][kk];
            acc[0][0] = fmaf(q0, k0, acc[0][0]); acc[0][1] = fmaf(q0, k1, acc[0][1]); acc[0][2] = fmaf(q0, k2, acc[0][2]);
            acc[1][0] = fmaf(q1, k0, acc[1][0]); acc[1][1] = fmaf(q1, k1, acc[1][1]); acc[1][2] = fmaf(q1, k2, acc[1][2]);
            acc[2][0] = fmaf(q2, k0, acc[2][0]); acc[2][1] = fmaf(q2, k1, acc[2][1]); acc[2][2] = fmaf(q2, k2, acc[2][2]);
        }
        __syncthreads();
    }
    float* out = sp + ((size_t)ks * 128 + bh) * (D_ * D_);
    #pragma unroll
    for (int i = 0; i < 3; ++i)
        #pragma unroll
        for (int j = 0; j < 3; ++j)
            out[(d0 + i) * D_ + e0 + j] = acc[i][j];
}

// ---------------- reduce partials, scale, softmax ----------------
__global__ __launch_bounds__(64) void softmax_k(
    const float* __restrict__ sp, const float* __restrict__ nqinv,
    const float* __restrict__ nkinv, const float* __restrict__ temp,
    float* __restrict__ attn)
{
    const int row = blockIdx.x;
    const int bh = row / D_, d = row % D_;
    const int h = bh & 7;
    const int e = threadIdx.x;
    float s = -INFINITY;
    if (e < D_) {
        float raw = 0.f;
        #pragma unroll
        for (int ks = 0; ks < 8; ++ks)
            raw += sp[((size_t)ks * 128 + bh) * (D_ * D_) + d * D_ + e];
        s = raw * nqinv[bh * D_ + d] * nkinv[bh * D_ + e] * temp[h];
    }
    float m = s;
    #pragma unroll
    for (int off = 1; off < 64; off <<= 1) m = fmaxf(m, __shfl_xor(m, off));
    float p = (e < D_) ? expf(s - m) : 0.f;
    float sum = p;
    #pragma unroll
    for (int off = 1; off < 64; off <<= 1) sum += __shfl_xor(sum, off);
    if (e < D_) attn[(size_t)bh * (D_ * D_) + d * D_ + e] = p / sum;
}

// ---------------- attn @ v -> bf16 transposed [pixel][384] into q-plane region ----------------
__global__ __launch_bounds__(256) void pv_kernel(
    float* __restrict__ buf, const float* __restrict__ attn)
{
    const int b = blockIdx.z, h = blockIdx.y;
    const int p0 = blockIdx.x * 512 + threadIdx.x * 2;
    __shared__ float a4[48][48];
    const float* ab = attn + ((size_t)b * 8 + h) * (D_ * D_);
    for (int i = threadIdx.x; i < D_ * D_; i += 256) ((float*)a4)[i] = ab[i];
    __syncthreads();
    const float* vbase = buf + ((size_t)b * C3_ + 2 * C_ + (size_t)h * D_) * HW_;
    float2 acc[48];
    #pragma unroll
    for (int d = 0; d < 48; ++d) { acc[d].x = 0.f; acc[d].y = 0.f; }
    #pragma unroll 1
    for (int e4 = 0; e4 < 12; ++e4) {
        float2 vv[4];
        #pragma unroll
        for (int j = 0; j < 4; ++j)
            vv[j] = *(const float2*)&vbase[(size_t)(e4 * 4 + j) * HW_ + p0];
        #pragma unroll
        for (int d = 0; d < 48; ++d) {
            float4 a = *(const float4*)&a4[d][e4 * 4];
            acc[d].x = fmaf(a.x, vv[0].x, fmaf(a.y, vv[1].x, fmaf(a.z, vv[2].x, fmaf(a.w, vv[3].x, acc[d].x))));
            acc[d].y = fmaf(a.x, vv[0].y, fmaf(a.y, vv[1].y, fmaf(a.z, vv[2].y, fmaf(a.w, vv[3].y, acc[d].y))));
        }
    }
    // write bf16 transposed: xt2[pixel][h*48+d] into batch-b q-plane region of buf
    unsigned short* xt2b = (unsigned short*)(buf + (size_t)b * C3_ * HW_);
    #pragma unroll
    for (int px = 0; px < 2; ++px) {
        unsigned short tmp[48];
        #pragma unroll
        for (int d = 0; d < 48; ++d) tmp[d] = f2bf(px ? acc[d].y : acc[d].x);
        uint4* dst = (uint4*)&xt2b[(size_t)(p0 + px) * C_ + h * D_];
        const uint4* src = (const uint4*)tmp;
        #pragma unroll
        for (int j = 0; j < 6; ++j) dst[j] = src[j];
    }
}

extern "C" void kernel_launch(void* const* d_in, const int* in_sizes, int n_in,
                              void* d_out, int out_size, void* d_ws, size_t ws_size,
                              hipStream_t stream)
{
    const float* x      = (const float*)d_in[0];
    const float* w_qkv  = (const float*)d_in[1];
    const float* w_dw   = (const float*)d_in[2];
    const float* w_proj = (const float*)d_in[3];
    const float* temp   = (const float*)d_in[4];
    float* out = (float*)d_out;

    float* buf   = (float*)d_ws;                          // 16*1152*4096 f32
    float* nqinv = buf + (size_t)B_ * C3_ * HW_;
    float* nkinv = nqinv + 6144;
    float* sp    = nkinv + 6144;                          // 8*128*2304 f32
    float* attn  = sp + (size_t)8 * 128 * D_ * D_;        // 128*2304 f32
    unsigned short* wqkv_bf  = (unsigned short*)(attn + (size_t)128 * D_ * D_);
    unsigned short* wproj_bf = wqkv_bf + (size_t)C3_ * C_;
    unsigned short* xt1      = wproj_bf + (size_t)C_ * C_; // 16*4096*384 bf16

    // 0) weight conversion + x transpose-convert
    conv_w_bf16<<<(C3_ * C_ / 4 + 255) / 256, 256, 0, stream>>>(w_qkv, wqkv_bf, C3_ * C_ / 4);
    conv_w_bf16<<<(C_ * C_ / 4 + 255) / 256, 256, 0, stream>>>(w_proj, wproj_bf, C_ * C_ / 4);
    transpose_to_bf16<<<dim3(64, 6, 16), 256, 0, stream>>>(x, xt1);

    // 1) qkv = w_qkv @ x  (bf16 MFMA)
    mfma_gemm<C3_><<<dim3(32, 9, 16), 256, 0, stream>>>(
        wqkv_bf, xt1, buf, (long long)HW_ * C_, (long long)C3_ * HW_);

    // 2) depthwise 3x3 SAME, in place
    dwconv_inplace<<<B_ * C3_, 256, 0, stream>>>(buf, w_dw);

    // 3) q,k row inverse-norms
    rownorm<<<2 * 6144, 256, 0, stream>>>(buf, nqinv, nkinv);

    // 4) raw scores partials (K split 8)
    scores_partial<<<dim3(128, 8), 256, 0, stream>>>(buf, sp);

    // 5) reduce + scale + softmax
    softmax_k<<<6144, 64, 0, stream>>>(sp, nqinv, nkinv, temp, attn);

    // 6) attn @ v -> bf16 transposed into q region (q dead after step 4)
    pv_kernel<<<dim3(8, 8, 16), 256, 0, stream>>>(buf, attn);

    // 7) out = w_proj @ attn_out (bf16 MFMA)
    mfma_gemm<C_><<<dim3(32, 3, 16), 256, 0, stream>>>(
        wproj_bf, (const unsigned short*)buf, out,
        (long long)C3_ * HW_ * 2, (long long)C_ * HW_);
}